// Round 1
// baseline (288.696 us; speedup 1.0000x reference)
//
#include <hip/hip_runtime.h>
#include <math.h>
#include <stdint.h>

#define BATCH 8192
#define NCLS  50257
#define BLK   256

// Online-logsumexp combine: (m1,s1) ⊕ (m2,s2) -> (max, rescaled sum)
__device__ __forceinline__ void lse_combine(float& m, float& s, float om, float os) {
    float nm = fmaxf(m, om);
    s = s * __expf(m - nm) + os * __expf(om - nm);
    m = nm;
}

__global__ __launch_bounds__(BLK) void row_lse_kernel(const float* __restrict__ x,
                                                      const int* __restrict__ tgt,
                                                      float* __restrict__ row_loss) {
    const int row = blockIdx.x;
    const int tid = threadIdx.x;
    const float* __restrict__ rp = x + (size_t)row * NCLS;

    // --- alignment peel: row base is only 4B-aligned (50257*4 % 16 != 0) ---
    const int mis  = (int)(((uintptr_t)rp & 15) >> 2);  // misalignment in elements (0..3)
    const int npre = (4 - mis) & 3;                     // scalar prefix count
    const int nvec = (NCLS - npre) >> 2;                // float4 count in main body
    const int base = npre + nvec * 4;                   // start of scalar tail

    float m = -INFINITY;
    float s = 0.0f;

    // scalar prefix (<=3 elements)
    if (tid < npre) {
        m = rp[tid];
        s = 1.0f;
    }

    // vectorized main body: 16 B/lane, stride-256 coalesced
    const float4* __restrict__ vp = (const float4*)(rp + npre);
    for (int i = tid; i < nvec; i += BLK) {
        float4 v = vp[i];
        float mv = fmaxf(fmaxf(v.x, v.y), fmaxf(v.z, v.w));
        float nm = fmaxf(m, mv);
        s = s * __expf(m - nm)
          + __expf(v.x - nm) + __expf(v.y - nm)
          + __expf(v.z - nm) + __expf(v.w - nm);
        m = nm;
    }

    // scalar tail (<=3 elements)
    for (int i = base + tid; i < NCLS; i += BLK) {
        float v = rp[i];
        float nm = fmaxf(m, v);
        s = s * __expf(m - nm) + __expf(v - nm);
        m = nm;
    }

    // --- wave reduction (64 lanes) ---
    #pragma unroll
    for (int off = 1; off < 64; off <<= 1) {
        float om = __shfl_xor(m, off);
        float os = __shfl_xor(s, off);
        lse_combine(m, s, om, os);
    }

    // --- cross-wave reduction (4 waves) ---
    __shared__ float sm[BLK / 64];
    __shared__ float ss[BLK / 64];
    const int wid  = tid >> 6;
    const int lane = tid & 63;
    if (lane == 0) { sm[wid] = m; ss[wid] = s; }
    __syncthreads();

    if (tid == 0) {
        float M = sm[0], S = ss[0];
        #pragma unroll
        for (int w = 1; w < BLK / 64; ++w) lse_combine(M, S, sm[w], ss[w]);
        const int t = tgt[row];
        const float xt = rp[t];
        row_loss[row] = (M + logf(S)) - xt;   // -(x[t] - logsumexp)
    }
}

__global__ __launch_bounds__(BLK) void mean_kernel(const float* __restrict__ row_loss,
                                                   float* __restrict__ out) {
    const int tid = threadIdx.x;
    float s = 0.0f;
    for (int i = tid; i < BATCH; i += BLK) s += row_loss[i];

    #pragma unroll
    for (int off = 1; off < 64; off <<= 1) s += __shfl_xor(s, off);

    __shared__ float sh[BLK / 64];
    if ((tid & 63) == 0) sh[tid >> 6] = s;
    __syncthreads();

    if (tid == 0) {
        float t = 0.0f;
        #pragma unroll
        for (int w = 0; w < BLK / 64; ++w) t += sh[w];
        out[0] = t / (float)BATCH;
    }
}

extern "C" void kernel_launch(void* const* d_in, const int* in_sizes, int n_in,
                              void* d_out, int out_size, void* d_ws, size_t ws_size,
                              hipStream_t stream) {
    const float* x   = (const float*)d_in[0];
    const int*   tgt = (const int*)d_in[1];
    float* out       = (float*)d_out;
    float* row_loss  = (float*)d_ws;   // 8192 floats = 32 KB scratch

    row_lse_kernel<<<BATCH, BLK, 0, stream>>>(x, tgt, row_loss);
    mean_kernel<<<1, BLK, 0, stream>>>(row_loss, out);
}

// Round 2
// 262.121 us; speedup vs baseline: 1.1014x; 1.1014x over previous
//
#include <hip/hip_runtime.h>
#include <math.h>
#include <stdint.h>

#define BATCH 8192
#define NCLS  50257
#define BLK   256

typedef float f4v __attribute__((ext_vector_type(4)));

// Online-logsumexp combine: (m1,s1) <- (m1,s1) ⊕ (m2,s2)
__device__ __forceinline__ void lse_combine(float& m, float& s, float om, float os) {
    float nm = fmaxf(m, om);
    s = s * __expf(m - nm) + os * __expf(om - nm);
    m = nm;
}

// Accumulate 4 elements into (m,s) with lazy (branchy) rescale.
__device__ __forceinline__ void acc4(float& m, float& s, f4v v) {
    float mv = fmaxf(fmaxf(v.x, v.y), fmaxf(v.z, v.w));   // -> v_max3_f32 + max
    if (mv > m) {                                         // rare after warm-up
        s *= __expf(m - mv);
        m = mv;
    }
    s += __expf(v.x - m) + __expf(v.y - m)
       + __expf(v.z - m) + __expf(v.w - m);
}

__global__ __launch_bounds__(BLK) void row_lse_kernel(const float* __restrict__ x,
                                                      const int* __restrict__ tgt,
                                                      float* __restrict__ row_loss) {
    const int row = blockIdx.x;
    const int tid = threadIdx.x;
    const float* __restrict__ rp = x + (size_t)row * NCLS;

    // target logit: issue the gather early so its latency hides under the loop
    const int   t  = tgt[row];
    const float xt = rp[t];

    // --- alignment peel: row base is only 4B-aligned (50257*4 % 16 != 0) ---
    const int mis  = (int)(((uintptr_t)rp & 15) >> 2);
    const int npre = (4 - mis) & 3;                 // scalar prefix count (0..3)
    const int nvec = (NCLS - npre) >> 2;            // float4 count
    const int base = npre + nvec * 4;               // scalar tail start

    float m0 = -INFINITY, s0 = 0.0f;
    float m1 = -INFINITY, s1 = 0.0f;

    // scalar prefix (<=3 elements)
    if (tid < npre) { m0 = rp[tid]; s0 = 1.0f; }

    // vectorized main body: 2x unrolled, two independent accumulators,
    // non-temporal 16B loads (streaming, read-once)
    const f4v* __restrict__ vp = (const f4v*)(rp + npre);
    int i = tid;
    for (; i + BLK < nvec; i += 2 * BLK) {
        f4v a = __builtin_nontemporal_load(vp + i);
        f4v b = __builtin_nontemporal_load(vp + i + BLK);
        acc4(m0, s0, a);
        acc4(m1, s1, b);
    }
    if (i < nvec) {
        f4v a = __builtin_nontemporal_load(vp + i);
        acc4(m0, s0, a);
    }

    // scalar tail (<=3 elements)
    for (int j = base + tid; j < NCLS; j += BLK) {
        float v = rp[j];
        if (v > m0) { s0 *= __expf(m0 - v); m0 = v; }
        s0 += __expf(v - m0);
    }

    // merge the two accumulators
    lse_combine(m0, s0, m1, s1);

    // --- wave reduction (64 lanes) ---
    #pragma unroll
    for (int off = 1; off < 64; off <<= 1) {
        float om = __shfl_xor(m0, off);
        float os = __shfl_xor(s0, off);
        lse_combine(m0, s0, om, os);
    }

    // --- cross-wave reduction (4 waves) ---
    __shared__ float sm[BLK / 64];
    __shared__ float ss[BLK / 64];
    const int wid  = tid >> 6;
    const int lane = tid & 63;
    if (lane == 0) { sm[wid] = m0; ss[wid] = s0; }
    __syncthreads();

    if (tid == 0) {
        float M = sm[0], S = ss[0];
        #pragma unroll
        for (int w = 1; w < BLK / 64; ++w) lse_combine(M, S, sm[w], ss[w]);
        row_loss[row] = (M + logf(S)) - xt;   // logsumexp(x) - x[target]
    }
}

__global__ __launch_bounds__(BLK) void mean_kernel(const float* __restrict__ row_loss,
                                                   float* __restrict__ out) {
    const int tid = threadIdx.x;
    float s = 0.0f;
    for (int i = tid; i < BATCH; i += BLK) s += row_loss[i];

    #pragma unroll
    for (int off = 1; off < 64; off <<= 1) s += __shfl_xor(s, off);

    __shared__ float sh[BLK / 64];
    if ((tid & 63) == 0) sh[tid >> 6] = s;
    __syncthreads();

    if (tid == 0) {
        float t = 0.0f;
        #pragma unroll
        for (int w = 0; w < BLK / 64; ++w) t += sh[w];
        out[0] = t / (float)BATCH;
    }
}

extern "C" void kernel_launch(void* const* d_in, const int* in_sizes, int n_in,
                              void* d_out, int out_size, void* d_ws, size_t ws_size,
                              hipStream_t stream) {
    const float* x   = (const float*)d_in[0];
    const int*   tgt = (const int*)d_in[1];
    float* out       = (float*)d_out;
    float* row_loss  = (float*)d_ws;   // 8192 floats = 32 KB scratch

    row_lse_kernel<<<BATCH, BLK, 0, stream>>>(x, tgt, row_loss);
    mean_kernel<<<1, BLK, 0, stream>>>(row_loss, out);
}